// Round 2
// baseline (448.693 us; speedup 1.0000x reference)
//
#include <hip/hip_runtime.h>

// Causal depthwise conv1d, NHC layout, fp32.
// out[b,t,c] = bias[c] + sum_{k=0..3} w[k,0,c] * x[b, t-3+k, c]
// B=4, T=8192, C=2048, K=4.
//
// Changes vs 437us kernel:
//  1. TCHUNK 8 -> 16: halo read-amplification 1.375x -> 1.1875x
//     (19 x-rows per 16 outputs instead of 11 per 8). All 19 loads are
//     independent and issued before any FMA -> ~19 KB in flight per wave,
//     no loop-carried dependency.
//  2. XCD-aware block swizzle: hardware round-robins blockIdx.x across the
//     8 XCDs, so adjacent tc-chunks (which share 3 halo rows) landed on
//     different, non-coherent L2s and re-fetched halos from HBM. Remap so
//     each XCD owns a contiguous tc-range -> halo rows are same-XCD L2 hits.
//  3. Non-temporal stores for out (never re-read) so the 256 MiB output
//     stream doesn't evict the x halo lines from L2. (Via native
//     ext_vector_type: the builtin rejects HIP_vector_type pointers.)
// Consecutive threads = consecutive c4 -> fully coalesced 16 B/lane.

constexpr int B = 4;
constexpr int T = 8192;
constexpr int C = 2048;
constexpr int C4 = C / 4;            // 512 float4 groups per row
constexpr int TCHUNK = 16;           // outputs per thread
constexpr int NCHUNK = T / TCHUNK;   // 512
constexpr int NLOAD = TCHUNK + 3;    // 19 x rows per thread

typedef float nfloat4 __attribute__((ext_vector_type(4)));

__global__ __launch_bounds__(256) void causal_conv1d_kernel(
    const float4* __restrict__ x,     // [B*T*C4]
    const float*  __restrict__ w,     // [K,1,C] flat: k*C + c
    const float*  __restrict__ bias,  // [C]
    float4* __restrict__ out)         // [B*T*C4]
{
    // XCD swizzle: grid = 4096 = 8 * 512, divisible by NXCD -> simple form
    // is bijective. XCD x gets logical blocks [x*512, (x+1)*512): a
    // contiguous run of (b, tc) chunks -> neighboring chunks' halo rows
    // live in the same XCD L2.
    const int bid = blockIdx.x;
    const int cpx = gridDim.x >> 3;                    // 512 blocks per XCD
    const int swz = (bid & 7) * cpx + (bid >> 3);

    const int idx  = swz * blockDim.x + threadIdx.x;
    const int c4   = idx & (C4 - 1);          // fastest-varying -> coalesced
    const int rest = idx >> 9;                // / 512 ; block-uniform
    const int tc   = rest & (NCHUNK - 1);     // & 511
    const int b    = rest >> 9;               // / 512
    const int t0   = tc * TCHUNK;

    const float4* xb = x   + (size_t)b * T * C4;
    float4*       ob = out + (size_t)b * T * C4;

    const float4 zero = make_float4(0.f, 0.f, 0.f, 0.f);
    float4 xv[NLOAD];

    // t0 is block-uniform -> no divergence. Issue every load up front.
    if (t0 != 0) {
#pragma unroll
        for (int i = 0; i < NLOAD; ++i)
            xv[i] = xb[(size_t)(t0 - 3 + i) * C4 + c4];
    } else {
        xv[0] = zero; xv[1] = zero; xv[2] = zero;
#pragma unroll
        for (int i = 3; i < NLOAD; ++i)
            xv[i] = xb[(size_t)(t0 - 3 + i) * C4 + c4];
    }

    // Per-channel weights (K=4) and bias, vectorized (40 KB total: L2-resident,
    // broadcast across tc so effectively free after first touch).
    const float4* w4 = (const float4*)w;
    const float4 w0 = w4[0 * C4 + c4];
    const float4 w1 = w4[1 * C4 + c4];
    const float4 w2 = w4[2 * C4 + c4];
    const float4 w3 = w4[3 * C4 + c4];
    const float4 bs = ((const float4*)bias)[c4];

#pragma unroll
    for (int j = 0; j < TCHUNK; ++j) {
        const float4 a0 = xv[j], a1 = xv[j + 1], a2 = xv[j + 2], a3 = xv[j + 3];
        float4 o;
        o.x = fmaf(w3.x, a3.x, fmaf(w2.x, a2.x, fmaf(w1.x, a1.x, fmaf(w0.x, a0.x, bs.x))));
        o.y = fmaf(w3.y, a3.y, fmaf(w2.y, a2.y, fmaf(w1.y, a1.y, fmaf(w0.y, a0.y, bs.y))));
        o.z = fmaf(w3.z, a3.z, fmaf(w2.z, a2.z, fmaf(w1.z, a1.z, fmaf(w0.z, a0.z, bs.z))));
        o.w = fmaf(w3.w, a3.w, fmaf(w2.w, a2.w, fmaf(w1.w, a1.w, fmaf(w0.w, a0.w, bs.w))));
        // out is write-once, never re-read: non-temporal keeps L2 for x halos.
        nfloat4 nv; nv.x = o.x; nv.y = o.y; nv.z = o.z; nv.w = o.w;
        __builtin_nontemporal_store(nv, (nfloat4*)&ob[(size_t)(t0 + j) * C4 + c4]);
    }
}

extern "C" void kernel_launch(void* const* d_in, const int* in_sizes, int n_in,
                              void* d_out, int out_size, void* d_ws, size_t ws_size,
                              hipStream_t stream) {
    const float4* x    = (const float4*)d_in[0];
    const float*  w    = (const float*)d_in[1];
    const float*  bias = (const float*)d_in[2];
    float4* out = (float4*)d_out;

    const int total_threads = B * NCHUNK * C4;   // 4*512*512 = 1,048,576
    const int block = 256;
    const int grid = total_threads / block;      // 4096
    causal_conv1d_kernel<<<grid, block, 0, stream>>>(x, w, bias, out);
}

// Round 3
// 436.390 us; speedup vs baseline: 1.0282x; 1.0282x over previous
//
#include <hip/hip_runtime.h>

// Causal depthwise conv1d, NHC layout, fp32.
// out[b,t,c] = bias[c] + sum_{k=0..3} w[k,0,c] * x[b, t-3+k, c]
// B=4, T=8192, C=2048, K=4.
//
// Round 3: register sliding-window strip to kill halo read-amplification.
//  - Each thread owns one float4 channel group (c4) and a 64-row t-strip,
//    processed as 8 chunks of 8 rows. The 3 boundary rows carry over in
//    registers, so x is read (64+3)/64 = 1.047x (baseline TCHUNK=8 was
//    1.375x => 96 MB of extra HBM read).
//  - MLP preserved: the next chunk's 8 loads are issued BEFORE the current
//    chunk's FMAs (one-chunk-deep prefetch). 16 waves/CU x 8 KB of loads in
//    flight = 128 KB/CU, ~12x the BW*latency product (25.8 GB/s * 375 ns
//    ~ 10 KB) -- latency fully hidden despite the carried window.
//    (Round-1's sliding window failed because it waited vmcnt(0) per row.)
//  - Reverted round-2's NT store + XCD swizzle (regressed: L3 is die-level
//    shared, so halo re-reads were already L3-absorbed; TCHUNK=16 blew the
//    128-VGPR occupancy step).
//  - Live set ~19 float4 + weights/bias (5 float4) + addressing ~= 100 VGPR
//    -> 4 waves/SIMD band preserved.
// Consecutive threads = consecutive c4 -> fully coalesced 16 B/lane.

constexpr int B = 4;
constexpr int T = 8192;
constexpr int C = 2048;
constexpr int C4 = C / 4;              // 512 float4 groups per row
constexpr int TCHUNK = 8;              // rows per compute chunk
constexpr int LSTRIP = 64;             // rows per thread
constexpr int NSTEPS = LSTRIP / TCHUNK;  // 8 chunks per strip
constexpr int NSTRIP = T / LSTRIP;     // 128 strips per (b, c4)

__global__ __launch_bounds__(256) void causal_conv1d_kernel(
    const float4* __restrict__ x,     // [B*T*C4]
    const float*  __restrict__ w,     // [K,1,C] flat: k*C + c
    const float*  __restrict__ bias,  // [C]
    float4* __restrict__ out)         // [B*T*C4]
{
    const int idx  = blockIdx.x * blockDim.x + threadIdx.x;
    const int c4   = idx & (C4 - 1);          // fastest-varying -> coalesced
    const int rest = idx >> 9;                // block-uniform
    const int s    = rest & (NSTRIP - 1);     // strip index 0..127
    const int b    = rest >> 7;               // / 128
    const int t0   = s * LSTRIP;

    const float4* xb = x   + (size_t)b * T * C4;
    float4*       ob = out + (size_t)b * T * C4;

    // Per-channel weights (K=4) and bias (40 KB total: cache-resident,
    // broadcast across strips so effectively free after first touch).
    const float4* w4 = (const float4*)w;
    const float4 w0 = w4[0 * C4 + c4];
    const float4 w1 = w4[1 * C4 + c4];
    const float4 w2 = w4[2 * C4 + c4];
    const float4 w3 = w4[3 * C4 + c4];
    const float4 bs = ((const float4*)bias)[c4];

    const float4 zero = make_float4(0.f, 0.f, 0.f, 0.f);

    // Window: rows t-3 .. t+7 relative to current chunk base.
    float4 win[TCHUNK + 3];

    // Prologue: first 11 rows (t0-3 .. t0+7). t0 is block-uniform.
    if (t0 != 0) {
#pragma unroll
        for (int i = 0; i < TCHUNK + 3; ++i)
            win[i] = xb[(size_t)(t0 - 3 + i) * C4 + c4];
    } else {
        win[0] = zero; win[1] = zero; win[2] = zero;
#pragma unroll
        for (int i = 0; i < TCHUNK; ++i)
            win[3 + i] = xb[(size_t)i * C4 + c4];
    }

#pragma unroll
    for (int step = 0; step < NSTEPS; ++step) {
        const int tbase = t0 + step * TCHUNK;

        // Prefetch next chunk's 8 rows BEFORE any FMA on the current chunk.
        float4 nxt[TCHUNK];
        if (step < NSTEPS - 1) {
#pragma unroll
            for (int i = 0; i < TCHUNK; ++i)
                nxt[i] = xb[(size_t)(tbase + TCHUNK + i) * C4 + c4];
        }

        // Compute + store the current 8 outputs from the register window.
#pragma unroll
        for (int j = 0; j < TCHUNK; ++j) {
            const float4 a0 = win[j], a1 = win[j + 1], a2 = win[j + 2], a3 = win[j + 3];
            float4 o;
            o.x = fmaf(w3.x, a3.x, fmaf(w2.x, a2.x, fmaf(w1.x, a1.x, fmaf(w0.x, a0.x, bs.x))));
            o.y = fmaf(w3.y, a3.y, fmaf(w2.y, a2.y, fmaf(w1.y, a1.y, fmaf(w0.y, a0.y, bs.y))));
            o.z = fmaf(w3.z, a3.z, fmaf(w2.z, a2.z, fmaf(w1.z, a1.z, fmaf(w0.z, a0.z, bs.z))));
            o.w = fmaf(w3.w, a3.w, fmaf(w2.w, a2.w, fmaf(w1.w, a1.w, fmaf(w0.w, a0.w, bs.w))));
            ob[(size_t)(tbase + j) * C4 + c4] = o;
        }

        // Slide the window: keep last 3 rows, append the prefetched 8.
        // Outer loop is fully unrolled -> compiler renames, no real moves.
        if (step < NSTEPS - 1) {
            win[0] = win[TCHUNK];
            win[1] = win[TCHUNK + 1];
            win[2] = win[TCHUNK + 2];
#pragma unroll
            for (int i = 0; i < TCHUNK; ++i)
                win[3 + i] = nxt[i];
        }
    }
}

extern "C" void kernel_launch(void* const* d_in, const int* in_sizes, int n_in,
                              void* d_out, int out_size, void* d_ws, size_t ws_size,
                              hipStream_t stream) {
    const float4* x    = (const float4*)d_in[0];
    const float*  w    = (const float*)d_in[1];
    const float*  bias = (const float*)d_in[2];
    float4* out = (float4*)d_out;

    const int total_threads = B * NSTRIP * C4;   // 4*128*512 = 262,144
    const int block = 256;
    const int grid = total_threads / block;      // 1024 blocks = 4/CU exactly
    causal_conv1d_kernel<<<grid, block, 0, stream>>>(x, w, bias, out);
}